// Round 13
// baseline (32.331 us; speedup 1.0000x reference)
//
#include <hip/hip_runtime.h>

#define HID   64
#define NHD   8
#define IT    4            // i's per block
#define WAVES 4            // 256 threads
#define JTW   32           // j's per wave (2 MFMA tiles of 16)
#define JT    (WAVES*JTW)  // 128 j's per block

typedef _Float16 f16x8 __attribute__((ext_vector_type(8)));
typedef float    f32x4 __attribute__((ext_vector_type(4)));

// K1: precompute u_all[b][n][64] (f16, no bias), a_all = u+b1 (f16), W2^T (f16).
// Removes ALL per-block staging from the hot kernel.
__global__ __launch_bounds__(256) void relpos_prep(
    const float* __restrict__ xyz, const float* __restrict__ W1,
    const float* __restrict__ b1,  const float* __restrict__ W2,
    _Float16* __restrict__ u_all, _Float16* __restrict__ a_all,
    _Float16* __restrict__ w2t, int N, int BN) {
  const int tid = threadIdx.x;
  if (blockIdx.x == 0) {
    for (int t = tid; t < NHD * HID; t += 256) {
      int k = t >> 6, h = t & 63;
      w2t[k * HID + h] = (_Float16)W2[h * NHD + k];
    }
  }
  int g = blockIdx.x * 256 + tid;
  if (g >= BN) return;
  int b = g / N, n = g - b * N;
  const float* xb = xyz + (size_t)b * 3 * N;
  float x0 = xb[n], x1 = xb[N + n], x2 = xb[2 * N + n];
  _Float16* up = u_all + (size_t)g * HID;
  _Float16* ap = a_all + (size_t)g * HID;
  #pragma unroll
  for (int c = 0; c < 8; ++c) {
    f16x8 uu, aa;
    #pragma unroll
    for (int e = 0; e < 8; ++e) {
      int h = c * 8 + e;
      float u = fmaf(x0, W1[h], fmaf(x1, W1[HID + h], x2 * W1[2 * HID + h]));
      uu[e] = (_Float16)u;
      aa[e] = (_Float16)(u + b1[h]);
    }
    *(f16x8*)(up + c * 8) = uu;
    *(f16x8*)(ap + c * 8) = aa;
  }
}

// K2: out[b,k,i,j] = sum_h relu(a_j[h] - u_i[h]) * W2[h,k] + b2[k]
// fp16 MFMA pipeline (validated r5-r12): aLo=W2^T rows 0..7, aHi=rows 8..15
// -> D rows 0..7 = lo j-tile, rows 8..15 = hi j-tile; all 64 lanes store.
// NO LDS, NO barrier, ~10 L2-hot vector loads of prologue -> 4096 small
// blocks backfill continuously, collapsing the scheduling tail that kept
// r2-r12 pinned at ~23-25us (avg occupancy was ~half of nominal).
__global__ __launch_bounds__(WAVES * 64, 4) void relpos_main(
    const _Float16* __restrict__ u_all, const _Float16* __restrict__ a_all,
    const _Float16* __restrict__ w2t,   const float* __restrict__ b2,
    float* __restrict__ out, int N) {

  const int tid  = threadIdx.x;
  const int wave = tid >> 6;
  const int lane = tid & 63;
  const int col  = lane & 15;
  const int hgrp = lane >> 4;
  const int b    = blockIdx.z;
  const int i0   = blockIdx.y * IT;
  const int j0   = blockIdx.x * JT + wave * JTW;

  const f16x8 z = {0, 0, 0, 0, 0, 0, 0, 0};

  // A fragments from the 1KB W2^T table (L1-resident)
  f16x8 aLo[2], aHi[2];
  #pragma unroll
  for (int kb = 0; kb < 2; ++kb) {
    f16x8 w = *(const f16x8*)(w2t + (col & 7) * HID + kb * 32 + hgrp * 8);
    aLo[kb] = (col < NHD) ? w : z;
    aHi[kb] = (col >= NHD) ? w : z;
  }

  // aj fragments (L2-hot a_all)
  f16x8 aj[2][2];
  #pragma unroll
  for (int t = 0; t < 2; ++t) {
    const _Float16* ap = a_all + ((size_t)(b * N + j0 + t * 16 + col)) * HID + hgrp * 8;
    aj[t][0] = *(const f16x8*)ap;
    aj[t][1] = *(const f16x8*)(ap + 32);
  }

  // u fragments for all IT i's (broadcast loads, L2-hot)
  f16x8 uf[IT][2];
  #pragma unroll
  for (int ii = 0; ii < IT; ++ii) {
    const _Float16* up = u_all + ((size_t)(b * N + i0 + ii)) * HID + hgrp * 8;
    uf[ii][0] = *(const f16x8*)up;
    uf[ii][1] = *(const f16x8*)(up + 32);
  }

  const int kbase = (hgrp & 1) << 2;
  float b2v[4];
  #pragma unroll
  for (int r = 0; r < 4; ++r) b2v[r] = b2[kbase + r];

  const size_t jj = (size_t)j0 + col + ((size_t)(lane >> 5) << 4);
  const size_t baseOff = ((size_t)(b * NHD + kbase) * N + i0) * N + jj;
  const size_t plane = (size_t)N * N;

  f32x4 vals[IT];
  #pragma unroll
  for (int q = 0; q < IT; ++q) {
    f16x8 d00 = __builtin_elementwise_max(aj[0][0] - uf[q][0], z);
    f16x8 d01 = __builtin_elementwise_max(aj[0][1] - uf[q][1], z);
    f16x8 d10 = __builtin_elementwise_max(aj[1][0] - uf[q][0], z);
    f16x8 d11 = __builtin_elementwise_max(aj[1][1] - uf[q][1], z);

    f32x4 cA = {b2v[0], b2v[1], b2v[2], b2v[3]};
    f32x4 cB = {0.f, 0.f, 0.f, 0.f};
    cA = __builtin_amdgcn_mfma_f32_16x16x32_f16(aLo[0], d00, cA, 0, 0, 0);
    cA = __builtin_amdgcn_mfma_f32_16x16x32_f16(aLo[1], d01, cA, 0, 0, 0);
    cB = __builtin_amdgcn_mfma_f32_16x16x32_f16(aHi[0], d10, cB, 0, 0, 0);
    cB = __builtin_amdgcn_mfma_f32_16x16x32_f16(aHi[1], d11, cB, 0, 0, 0);
    vals[q] = cA + cB;
  }

  #pragma unroll
  for (int r = 0; r < 4; ++r) {
    const size_t po = baseOff + (size_t)r * plane;
    #pragma unroll
    for (int q = 0; q < IT; ++q)
      out[po + (size_t)q * N] = vals[q][r];
  }
}

extern "C" void kernel_launch(void* const* d_in, const int* in_sizes, int n_in,
                              void* d_out, int out_size, void* d_ws, size_t ws_size,
                              hipStream_t stream) {
  const float* xyz = (const float*)d_in[0];
  const float* W1  = (const float*)d_in[1];
  const float* b1  = (const float*)d_in[2];
  const float* W2  = (const float*)d_in[3];
  const float* b2  = (const float*)d_in[4];
  float* out = (float*)d_out;

  const long long in0 = in_sizes[0];
  const int N = (int)((3LL * (long long)out_size) / (8LL * in0));
  const int B = (int)(in0 / (3LL * N));
  const int BN = B * N;

  _Float16* u_all = (_Float16*)d_ws;
  _Float16* a_all = (_Float16*)((char*)d_ws + (size_t)BN * HID * 2);
  _Float16* w2t   = (_Float16*)((char*)d_ws + (size_t)BN * HID * 4);

  relpos_prep<<<(BN + 255) / 256, 256, 0, stream>>>(
      xyz, W1, b1, W2, u_all, a_all, w2t, N, BN);

  dim3 grid(N / JT, N / IT, B);
  relpos_main<<<grid, WAVES * 64, 0, stream>>>(u_all, a_all, w2t, b2, out, N);
}

// Round 14
// 28.529 us; speedup vs baseline: 1.1333x; 1.1333x over previous
//
#include <hip/hip_runtime.h>

#define HID   64
#define NHD   8
#define IT    8            // i's per block -> grid (2, 128, 2) = 512 blocks
#define WAVES 8            // 512 threads; wave w also drains plane k=w
#define NPAIR 2            // tile-pairs (32 j) per wave -> 64 j per wave
#define JBLK  512          // j's per block

typedef _Float16 f16x8 __attribute__((ext_vector_type(8)));
typedef float    f32x4 __attribute__((ext_vector_type(4)));

// out[b,k,i,j] = sum_h relu( (u_j[h]+b1[h]) - u_i[h] ) * W2[h,k] + b2[k]
// Compute: r12's validated fp16 MFMA pipeline (aLo=W2^T rows0..7 / aHi=rows
// 8..15 -> D rows 0..7 = lo j-tile, 8..15 = hi j-tile; LDS-staged W2; b2 in
// acc init). NEW: per-i pipelined LDS transpose drain — block deposits its
// (8k x 512j) i-slab into a ping-pong 16KB LDS tile, then wave w drains plane
// k=w as two FULL-WAVE 1KB dwordx4 stores (2KB contiguous, page-local run).
// Isolates the one invariant of r2-r12: the 128B-granule plane-scattered
// store image (vs the 6 TB/s fill's wide ascending runs).
__global__ __launch_bounds__(WAVES * 64, 4) void relposenc_rowdrain(
    const float* __restrict__ xyz, const float* __restrict__ W1,
    const float* __restrict__ b1,  const float* __restrict__ W2,
    const float* __restrict__ b2,  float* __restrict__ out, int N) {

  __shared__ float    sW1b1[4][HID];
  __shared__ float    sW2p[HID][NHD + 1];
  __shared__ float    sB2[NHD];
  __shared__ _Float16 sU[IT][HID];
  __shared__ float    sT[2][NHD][JBLK];   // ping-pong transpose tile, 2x16KB

  const int tid  = threadIdx.x;
  const int wave = tid >> 6;
  const int lane = tid & 63;
  const int col  = lane & 15;
  const int hgrp = lane >> 4;
  const int b    = blockIdx.z;
  const int i0   = blockIdx.y * IT;
  const int jb0  = blockIdx.x * JBLK;          // block j-base
  const int jwb  = jb0 + wave * (NPAIR * 32);  // wave j-base

  const float* xb = xyz + (size_t)b * 3 * N;

  // ---- coalesced staging (validated r12) ----
  sW2p[tid >> 3][tid & 7] = W2[tid];
  if (tid < 4 * HID) {
    int r = tid >> 6, h = tid & 63;
    sW1b1[r][h] = (r < 3) ? W1[r * HID + h] : b1[h];
  }
  if (tid < NHD) sB2[tid] = b2[tid];
  {
    int ii = tid >> 6, h = tid & 63;   // IT*HID == 512 exactly
    int i  = i0 + ii;
    float u = fmaf(xb[i], W1[h],
              fmaf(xb[N + i], W1[HID + h],
                   xb[2 * N + i] * W1[2 * HID + h]));
    sU[ii][h] = (_Float16)u;
  }

  __syncthreads();

  // ---- fragments from LDS ----
  f16x8 aLo[2], aHi[2];
  #pragma unroll
  for (int kb = 0; kb < 2; ++kb)
    #pragma unroll
    for (int e = 0; e < 8; ++e) {
      int h = kb * 32 + hgrp * 8 + e;
      aLo[kb][e] = (_Float16)((col < NHD)  ? sW2p[h][col]     : 0.f);
      aHi[kb][e] = (_Float16)((col >= NHD) ? sW2p[h][col - 8] : 0.f);
    }
  const int kbase = (hgrp & 1) << 2;
  float b2v[4];
  #pragma unroll
  for (int r = 0; r < 4; ++r) b2v[r] = sB2[kbase + r];

  // aj for this wave's 2 pairs x 2 tiles
  f16x8 aj[NPAIR][2][2];
  #pragma unroll
  for (int p = 0; p < NPAIR; ++p)
    #pragma unroll
    for (int t = 0; t < 2; ++t) {
      int j = jwb + p * 32 + t * 16 + col;
      float x0 = xb[j], x1 = xb[N + j], x2 = xb[2 * N + j];
      #pragma unroll
      for (int kb = 0; kb < 2; ++kb)
        #pragma unroll
        for (int e = 0; e < 8; ++e) {
          int h = kb * 32 + hgrp * 8 + e;
          float v = fmaf(x0, sW1b1[0][h],
                    fmaf(x1, sW1b1[1][h],
                    fmaf(x2, sW1b1[2][h], sW1b1[3][h])));
          aj[p][t][kb][e] = (_Float16)v;
        }
    }

  // LDS deposit j-index (block-local) per pair; drain geometry
  const int jdep = wave * (NPAIR * 32) + col + ((lane >> 5) << 4);
  const f16x8 z = {0, 0, 0, 0, 0, 0, 0, 0};

  float* drainDst = out + (((size_t)(b * NHD + wave)) * N + i0) * N + jb0;

  int buf = 0;
  for (int ii = 0; ii < IT; ++ii) {
    f16x8 u0 = *(const f16x8*)&sU[ii][hgrp * 8];
    f16x8 u1 = *(const f16x8*)&sU[ii][32 + hgrp * 8];

    #pragma unroll
    for (int p = 0; p < NPAIR; ++p) {
      f16x8 d00 = __builtin_elementwise_max(aj[p][0][0] - u0, z);
      f16x8 d01 = __builtin_elementwise_max(aj[p][0][1] - u1, z);
      f16x8 d10 = __builtin_elementwise_max(aj[p][1][0] - u0, z);
      f16x8 d11 = __builtin_elementwise_max(aj[p][1][1] - u1, z);

      f32x4 cA = {b2v[0], b2v[1], b2v[2], b2v[3]};
      f32x4 cB = {0.f, 0.f, 0.f, 0.f};
      cA = __builtin_amdgcn_mfma_f32_16x16x32_f16(aLo[0], d00, cA, 0, 0, 0);
      cA = __builtin_amdgcn_mfma_f32_16x16x32_f16(aLo[1], d01, cA, 0, 0, 0);
      cB = __builtin_amdgcn_mfma_f32_16x16x32_f16(aHi[0], d10, cB, 0, 0, 0);
      cB = __builtin_amdgcn_mfma_f32_16x16x32_f16(aHi[1], d11, cB, 0, 0, 0);
      f32x4 v = cA + cB;

      #pragma unroll
      for (int r = 0; r < 4; ++r)
        sT[buf][kbase + r][p * 32 + jdep] = v[r];
    }

    __syncthreads();

    // drain plane k=wave for row i0+ii: two full-wave 1KB dwordx4 stores
    {
      const float* src = &sT[buf][wave][0];
      float* dst = drainDst + (size_t)ii * N;
      f32x4 v0 = *(const f32x4*)(src + lane * 4);
      f32x4 v1 = *(const f32x4*)(src + 256 + lane * 4);
      *(f32x4*)(dst + lane * 4) = v0;
      *(f32x4*)(dst + 256 + lane * 4) = v1;
    }
    buf ^= 1;
  }
}

extern "C" void kernel_launch(void* const* d_in, const int* in_sizes, int n_in,
                              void* d_out, int out_size, void* d_ws, size_t ws_size,
                              hipStream_t stream) {
  const float* xyz = (const float*)d_in[0];
  const float* W1  = (const float*)d_in[1];
  const float* b1  = (const float*)d_in[2];
  const float* W2  = (const float*)d_in[3];
  const float* b2  = (const float*)d_in[4];
  float* out = (float*)d_out;

  const long long in0 = in_sizes[0];
  const int N = (int)((3LL * (long long)out_size) / (8LL * in0));
  const int B = (int)(in0 / (3LL * N));

  dim3 grid(N / JBLK, N / IT, B);
  relposenc_rowdrain<<<grid, WAVES * 64, 0, stream>>>(xyz, W1, b1, W2, b2, out, N);
}

// Round 15
// 21.230 us; speedup vs baseline: 1.5229x; 1.3438x over previous
//
#include <hip/hip_runtime.h>

#define HID   64
#define NHD   8
#define IT    16          // i's per block -> 512 blocks = 2/CU
#define WAVES 8
#define JTW   32          // j's per wave (2 MFMA tiles of 16)
#define JT    (WAVES*JTW) // 256 j's per block

typedef _Float16 f16x8 __attribute__((ext_vector_type(8)));
typedef float    f32x4 __attribute__((ext_vector_type(4)));

// out[b,k,i,j] = sum_h relu( (u_j[h]+b1[h]) - u_i[h] ) * W2[h,k] + b2[k]
// TRANSPOSED orientation vs r12: A = relu-diff (M=j, 16 rows all useful; the
// per-lane fragment values are IDENTICAL to r12's B-operand), B = W2 natural
// (N=heads, cols 8..15 zero), D: col=lane&15=k, row=(lane>>4)*4+reg = 4
// CONSECUTIVE j per lane -> one global_store_dwordx4 per j-tile (col<8 mask).
// Same MFMA count / VALU / segment count as r12; store INSTRUCTIONS halve and
// each carries 4x bytes per outstanding-queue slot — isolating the per-inst
// store-completion-slot limit inferred from r8 (marginal 8.3 TB/s vs avg 2.9,
// all pipes idle, TLP-insensitive).
__global__ __launch_bounds__(WAVES * 64, 4) void relposenc_x4(
    const float* __restrict__ xyz, const float* __restrict__ W1,
    const float* __restrict__ b1,  const float* __restrict__ W2,
    const float* __restrict__ b2,  float* __restrict__ out, int N) {

  __shared__ float    sW1b1[4][HID];
  __shared__ float    sW2p[HID][NHD + 1];
  __shared__ float    sB2[NHD];
  __shared__ _Float16 sU[IT][HID];

  const int tid  = threadIdx.x;
  const int wave = tid >> 6;
  const int lane = tid & 63;
  const int col  = lane & 15;
  const int hgrp = lane >> 4;
  const int b    = blockIdx.z;
  const int i0   = blockIdx.y * IT;
  const int j0   = blockIdx.x * JT + wave * JTW;

  const float* xb = xyz + (size_t)b * 3 * N;

  // ---- coalesced staging (validated r12) ----
  sW2p[tid >> 3][tid & 7] = W2[tid];
  if (tid < 4 * HID) {
    int r = tid >> 6, h = tid & 63;
    sW1b1[r][h] = (r < 3) ? W1[r * HID + h] : b1[h];
  }
  if (tid < NHD) sB2[tid] = b2[tid];
  for (int t = tid; t < IT * HID; t += WAVES * 64) {
    int ii = t >> 6, h = t & 63;
    int i  = i0 + ii;
    float u = fmaf(xb[i], W1[h],
              fmaf(xb[N + i], W1[HID + h],
                   xb[2 * N + i] * W1[2 * HID + h]));
    sU[ii][h] = (_Float16)u;
  }

  __syncthreads();

  // ---- B fragments: W2 natural layout; cols (heads) 8..15 zero ----
  f16x8 w2f[2];
  #pragma unroll
  for (int kb = 0; kb < 2; ++kb)
    #pragma unroll
    for (int e = 0; e < 8; ++e) {
      int h = kb * 32 + hgrp * 8 + e;
      w2f[kb][e] = (_Float16)((col < NHD) ? sW2p[h][col] : 0.f);
    }
  const float b2s = sB2[col & 7];

  // ---- aj = u_j + b1 (f16) for this lane's 2 j's (IDENTICAL to r12) ----
  f16x8 aj[2][2];
  #pragma unroll
  for (int t = 0; t < 2; ++t) {
    int j = j0 + t * 16 + col;
    float x0 = xb[j], x1 = xb[N + j], x2 = xb[2 * N + j];
    #pragma unroll
    for (int kb = 0; kb < 2; ++kb)
      #pragma unroll
      for (int e = 0; e < 8; ++e) {
        int h = kb * 32 + hgrp * 8 + e;
        float v = fmaf(x0, sW1b1[0][h],
                  fmaf(x1, sW1b1[1][h],
                  fmaf(x2, sW1b1[2][h], sW1b1[3][h])));
        aj[t][kb][e] = (_Float16)v;
      }
  }

  // store geometry: lane (col<8, hgrp) owns plane k=col, j = j0 + t*16 + hgrp*4
  const size_t baseOff =
      ((size_t)(b * NHD + (col & 7)) * N + i0) * N + j0 + hgrp * 4;

  const f16x8 z = {0, 0, 0, 0, 0, 0, 0, 0};

  for (int ii = 0; ii < IT; ++ii) {
    f16x8 u0 = *(const f16x8*)&sU[ii][hgrp * 8];
    f16x8 u1 = *(const f16x8*)&sU[ii][32 + hgrp * 8];

    f16x8 d00 = __builtin_elementwise_max(aj[0][0] - u0, z);
    f16x8 d01 = __builtin_elementwise_max(aj[0][1] - u1, z);
    f16x8 d10 = __builtin_elementwise_max(aj[1][0] - u0, z);
    f16x8 d11 = __builtin_elementwise_max(aj[1][1] - u1, z);

    f32x4 c0 = {b2s, b2s, b2s, b2s};   // b2 folded into acc init
    f32x4 c1 = {b2s, b2s, b2s, b2s};
    c0 = __builtin_amdgcn_mfma_f32_16x16x32_f16(d00, w2f[0], c0, 0, 0, 0);
    c0 = __builtin_amdgcn_mfma_f32_16x16x32_f16(d01, w2f[1], c0, 0, 0, 0);
    c1 = __builtin_amdgcn_mfma_f32_16x16x32_f16(d10, w2f[0], c1, 0, 0, 0);
    c1 = __builtin_amdgcn_mfma_f32_16x16x32_f16(d11, w2f[1], c1, 0, 0, 0);

    if (col < NHD) {
      float* p = out + baseOff + (size_t)ii * N;
      *(f32x4*)p        = c0;   // j0 + hgrp*4 .. +3   (16B, dwordx4)
      *(f32x4*)(p + 16) = c1;   // j0 + 16 + hgrp*4 .. (16B, dwordx4)
    }
  }
}

extern "C" void kernel_launch(void* const* d_in, const int* in_sizes, int n_in,
                              void* d_out, int out_size, void* d_ws, size_t ws_size,
                              hipStream_t stream) {
  const float* xyz = (const float*)d_in[0];
  const float* W1  = (const float*)d_in[1];
  const float* b1  = (const float*)d_in[2];
  const float* W2  = (const float*)d_in[3];
  const float* b2  = (const float*)d_in[4];
  float* out = (float*)d_out;

  const long long in0 = in_sizes[0];
  const int N = (int)((3LL * (long long)out_size) / (8LL * in0));
  const int B = (int)(in0 / (3LL * N));

  dim3 grid(N / JT, N / IT, B);
  relposenc_x4<<<grid, WAVES * 64, 0, stream>>>(xyz, W1, b1, W2, b2, out, N);
}